// Round 6
// baseline (279.699 us; speedup 1.0000x reference)
//
#include <hip/hip_runtime.h>
#include <cstdint>

typedef unsigned short u16;
typedef unsigned int u32;

typedef short bf16x8 __attribute__((ext_vector_type(8)));
typedef float f32x4 __attribute__((ext_vector_type(4)));

#define LN2 0.69314718055994530942f
#define LOG2E 1.44269504088896340736f
#define INFF __builtin_inff()

__device__ __forceinline__ u16 f2bf(float f) {
  u32 u = __float_as_uint(f);
  u = (u + 0x7fffu + ((u >> 16) & 1u)) >> 16;
  return (u16)u;
}
__device__ __forceinline__ u32 pack2bf(float a, float b) {
  u32 ta = __float_as_uint(a) + 0x8000u;
  u32 tb = __float_as_uint(b) + 0x8000u;
  return __builtin_amdgcn_perm(tb, ta, 0x07060302u);
}
// RNE-packed pair (matches f2bf numerics; used for V so attn sees identical values)
__device__ __forceinline__ u32 pack2bf_rne(float a, float b) {
  return (u32)f2bf(a) | ((u32)f2bf(b) << 16);
}

#if __has_builtin(__builtin_amdgcn_global_load_lds)
#define HAVE_GLDS 1
__device__ __forceinline__ void glds16(const u16* g, u16* l) {
  __builtin_amdgcn_global_load_lds((const __attribute__((address_space(1))) void*)g,
                                   (__attribute__((address_space(3))) void*)l, 16, 0, 0);
}
#else
#define HAVE_GLDS 0
#endif

// stage 1KB per wave: per-lane global source gperlane (16B each), wave-uniform
// LDS dest lwave (HW adds lane*16B for glds; fallback does it manually).
__device__ __forceinline__ void stage1k(const u16* gperlane, u16* lwave, int lane) {
#if HAVE_GLDS
  (void)lane;
  glds16(gperlane, lwave);
#else
  *(uint4*)(lwave + lane * 8) = *(const uint4*)gperlane;
#endif
}

// XOR-swizzled LDS addressing for [R][64] u16 tiles (128B rows).
// byte ^= ((row&7)<<4). Measured: kills the stride-128B same-bank pattern
// (SQ_LDS_BANK_CONFLICT 5.9M -> 1.08M). K/V arrive in global memory ALREADY
// swizzled (GEMM epilogue applies the XOR), so staging is a pure linear async
// copy and only the reads use swzp.
__device__ __forceinline__ u16* swzp(u16* base, int row, int bc) {
  return (u16*)((char*)base + row * 128 + (bc ^ ((row & 7) << 4)));
}

// ---------------- prep kernels ----------------

__global__ void k_convert_x(const float* __restrict__ in, u16* __restrict__ out, int n4) {
  int i = blockIdx.x * blockDim.x + threadIdx.x;
  if (i < n4) {
    float4 v = ((const float4*)in)[i];
    ushort4 o;
    o.x = f2bf(v.x); o.y = f2bf(v.y); o.z = f2bf(v.z); o.w = f2bf(v.w);
    ((ushort4*)out)[i] = o;
  }
}

__global__ void k_transpose_bf(const float* __restrict__ in, u16* __restrict__ out, int R, int C) {
  __shared__ float t[32][33];
  int c0 = blockIdx.x * 32, r0 = blockIdx.y * 32;
  int tx = threadIdx.x, ty = threadIdx.y;
#pragma unroll
  for (int k = 0; k < 4; k++) t[ty + 8 * k][tx] = in[(size_t)(r0 + ty + 8 * k) * C + c0 + tx];
  __syncthreads();
#pragma unroll
  for (int k = 0; k < 4; k++) out[(size_t)(c0 + ty + 8 * k) * R + r0 + tx] = f2bf(t[tx][ty + 8 * k]);
}

__global__ void k_tables(const float* __restrict__ cP, const float* __restrict__ lP,
                         float* __restrict__ ig2) {
  int t = blockIdx.x * blockDim.x + threadIdx.x;
  float c = fabsf(cP[0]);
  if (t < 2048) {
    float lm = lP[0];
    float thr = fabsf(lm * 512.0f);
    float pn = fmaxf((float)t, thr);
    float den = logf(c * pn + 1.0f) + 1e-6f;
    ig2[t] = LN2 / den;
  }
}

__global__ void k_segments(const float* __restrict__ w1, const float* __restrict__ b1,
                           const float* __restrict__ w2, const float* __restrict__ b2,
                           float* __restrict__ segX, float* __restrict__ segA,
                           float* __restrict__ segB, int* __restrict__ segU) {
  __shared__ float xs[32];
  __shared__ float srt[32];
  __shared__ float uniq[32];
  __shared__ int uCnt;
  int t = threadIdx.x;
  if (t < 32) {
    float w = w1[t], b = b1[t];
    xs[t] = (w != 0.0f) ? (-b / w) : INFF;
  }
  __syncthreads();
  if (t < 32) {
    float x = xs[t];
    int r = 0;
    for (int v = 0; v < 32; v++) {
      float xv = xs[v];
      if (xv < x || (xv == x && v < t)) r++;
    }
    srt[r] = x;
  }
  __syncthreads();
  if (t == 0) {
    int u = 0;
    for (int i = 0; i < 32; i++) {
      float v = srt[i];
      if (v < 3.0e38f && (u == 0 || v != uniq[u - 1])) uniq[u++] = v;
    }
    uCnt = u;
    segU[0] = u;
  }
  __syncthreads();
  int u = uCnt;
  if (t < u) segX[t] = uniq[t];
  for (int idx = t; idx < (u + 1) * 16; idx += blockDim.x) {
    int j = idx >> 4, h = idx & 15;
    float p;
    if (u == 0) p = 0.0f;
    else if (j == 0) p = uniq[0] - 1.0f;
    else if (j == u) p = uniq[u - 1] + 1.0f;
    else p = 0.5f * (uniq[j - 1] + uniq[j]);
    float A = b2[h], B = 0.0f;
    for (int w = 0; w < 32; w++) {
      float w1w = w1[w], b1w = b1[w], w2wh = w2[w * 16 + h];
      if (w1w != 0.0f) {
        if (fmaf(w1w, p, b1w) > 0.0f) { B += w1w * w2wh; A += b1w * w2wh; }
      } else if (b1w > 0.0f) {
        A += b1w * w2wh;
      }
    }
    segA[j * 16 + h] = A;
    segB[j * 16 + h] = B;
  }
}

// ---------------- GEMM:  C(MxN) = A(MxK) @ BT(NxK)^T ----------------
// MODE 0 (QKV): Q -> [bh][t][d] linear; K -> [bh][t][d] with per-row byte
// swizzle ^((t&7)<<4); V -> TRANSPOSED [bh][d][t] with per-row byte swizzle
// ^((d&7)<<4). The swizzled layouts make k_attn's LDS staging a pure linear
// async copy (global_load_lds) with conflict-free ds_read_b128 on the read.
template <int MODE, int BN>
__launch_bounds__(256, 3)
__global__ void k_gemm(const u16* __restrict__ A, const u16* __restrict__ BT,
                       const float* __restrict__ bias, float* __restrict__ outF,
                       u16* __restrict__ outQ, u16* __restrict__ outK, u16* __restrict__ outV,
                       int M, int N, int K) {
  constexpr int NT = BN / 32;
  constexpr int NCH = BN / 32;
  __shared__ u16 As[128 * 64];
  __shared__ u16 Bs[BN * 64];
  const int tid = threadIdx.x;
  const int lane = tid & 63, wave = tid >> 6;
  const int li = lane & 15, quad = lane >> 4;
  const int wrow = (wave >> 1) * 64, wcol = (wave & 1) * (BN / 2);
  const int rb = blockIdx.y * 128, cb = blockIdx.x * BN;

  f32x4 acc[4][NT];
#pragma unroll
  for (int i = 0; i < 4; i++)
#pragma unroll
    for (int j = 0; j < NT; j++) acc[i][j] = (f32x4){0.f, 0.f, 0.f, 0.f};

#if HAVE_GLDS
  const u16* gA = A + (size_t)(rb + (tid >> 3)) * K + (tid & 7) * 8;
  const u16* gB = BT + (size_t)(cb + (tid >> 3)) * K + (tid & 7) * 8;
  u16* lA = As + wave * 512;
  u16* lB = Bs + wave * 512;

  for (int k0 = 0; k0 < K; k0 += 64) {
    __syncthreads();
#pragma unroll
    for (int ch = 0; ch < 4; ch++) glds16(gA + (size_t)ch * 32 * K + k0, lA + ch * 2048);
#pragma unroll
    for (int ch = 0; ch < NCH; ch++) glds16(gB + (size_t)ch * 32 * K + k0, lB + ch * 2048);
    __syncthreads();
#pragma unroll
    for (int c = 0; c < 2; c++) {
      bf16x8 af[4], bfr[NT];
#pragma unroll
      for (int mt = 0; mt < 4; mt++)
        af[mt] = *(const bf16x8*)(&As[(wrow + mt * 16 + li) * 64 + c * 32 + quad * 8]);
#pragma unroll
      for (int nt = 0; nt < NT; nt++)
        bfr[nt] = *(const bf16x8*)(&Bs[(wcol + nt * 16 + li) * 64 + c * 32 + quad * 8]);
#pragma unroll
      for (int mt = 0; mt < 4; mt++)
#pragma unroll
        for (int nt = 0; nt < NT; nt++)
          acc[mt][nt] = __builtin_amdgcn_mfma_f32_16x16x32_bf16(af[mt], bfr[nt], acc[mt][nt], 0, 0, 0);
    }
  }
#else
  for (int k0 = 0; k0 < K; k0 += 64) {
    __syncthreads();
    for (int idx = tid * 8; idx < 128 * 64; idx += 256 * 8) {
      int rr = idx >> 6, cc = idx & 63;
      *(uint4*)(&As[idx]) = *(const uint4*)(A + (size_t)(rb + rr) * K + k0 + cc);
    }
    for (int idx = tid * 8; idx < BN * 64; idx += 256 * 8) {
      int rr = idx >> 6, cc = idx & 63;
      *(uint4*)(&Bs[idx]) = *(const uint4*)(BT + (size_t)(cb + rr) * K + k0 + cc);
    }
    __syncthreads();
#pragma unroll
    for (int c = 0; c < 2; c++) {
      bf16x8 af[4], bfr[NT];
#pragma unroll
      for (int mt = 0; mt < 4; mt++)
        af[mt] = *(const bf16x8*)(&As[(wrow + mt * 16 + li) * 64 + c * 32 + quad * 8]);
#pragma unroll
      for (int nt = 0; nt < NT; nt++)
        bfr[nt] = *(const bf16x8*)(&Bs[(wcol + nt * 16 + li) * 64 + c * 32 + quad * 8]);
#pragma unroll
      for (int mt = 0; mt < 4; mt++)
#pragma unroll
        for (int nt = 0; nt < NT; nt++)
          acc[mt][nt] = __builtin_amdgcn_mfma_f32_16x16x32_bf16(af[mt], bfr[nt], acc[mt][nt], 0, 0, 0);
    }
  }
#endif

#pragma unroll
  for (int mt = 0; mt < 4; mt++)
#pragma unroll
    for (int nt = 0; nt < NT; nt++) {
      const int col = cb + wcol + nt * 16 + li;
      const int row0 = rb + wrow + mt * 16 + quad * 4;
      float v[4];
#pragma unroll
      for (int r = 0; r < 4; r++) v[r] = acc[mt][nt][r] + bias[col];
      if (MODE == 0) {
        const int bb = row0 >> 11, tt0 = row0 & 2047;
        const int sel = col >> 10, w = col & 1023, hh = w >> 6, dd = w & 63;
        if (sel == 0) {
          u16* dst = outQ + ((size_t)((bb * 16 + hh) * 2048 + tt0)) * 64 + dd;
#pragma unroll
          for (int r = 0; r < 4; r++) dst[(size_t)r * 64] = f2bf(v[r]);
        } else if (sel == 1) {
          // K: row-swizzled [bh][t][d]
          u16* base = outK + ((size_t)((bb * 16 + hh) * 2048 + tt0)) * 64;
#pragma unroll
          for (int r = 0; r < 4; r++) {
            int tt = tt0 + r;
            base[(size_t)r * 64 + (dd ^ (((tt & 7)) << 3))] = f2bf(v[r]);
          }
        } else {
          // V: transposed+swizzled [bh][d][t], 4 consecutive t -> one 8B store
          u16* vrow = outV + ((size_t)((bb * 16 + hh) * 64 + dd)) * 2048;
          uint2 pk;
          pk.x = pack2bf_rne(v[0], v[1]);
          pk.y = pack2bf_rne(v[2], v[3]);
          *(uint2*)(vrow + (tt0 ^ ((dd & 7) << 3))) = pk;
        }
      } else {
#pragma unroll
        for (int r = 0; r < 4; r++) outF[(size_t)(row0 + r) * N + col] = v[r];
      }
    }
}

// ---------------- flash attention, S^T formulation, 2 q-groups/wave --------
// Round-5 finding: the 2-q-group structure spilled under __launch_bounds__
// (256,2) -- the 2nd arg caps COMBINED arch+acc regs at 256/wave; allocator
// gave 128 arch + 128 acc and spilled 18MB/launch to scratch (WRITE_SIZE
// 8->26MB, dur 77->88.6us). Fix: (256,1) -> cap 512. Grid gives 2 blocks/CU
// (8 waves = 2 waves/SIMD), which reg usage <=256/wave still supports; LDS
// 48.5KB allows 3. One variable changed vs round 5.
// Structure rationale (round 4): LDS-BW + chain-latency bound. Each wave owns
// 32 q-rows as two 16-row groups 64 apart: every kf/vf LDS fragment read
// feeds TWO MFMAs, barriers+staging per unit work halve, two independent
// softmax chains give ILP. Bias via v_log_f32 in registers (no LDS table).
__launch_bounds__(256, 1)
__global__ void k_attn(const u16* __restrict__ Q, const u16* __restrict__ K,
                       const u16* __restrict__ Vt, u16* __restrict__ Y,
                       const float* __restrict__ ig2, const float* __restrict__ cP,
                       const float* __restrict__ segX, const float* __restrict__ segA,
                       const float* __restrict__ segB, const int* __restrict__ segU) {
  __shared__ u16 KsB[2 * 4096];   // double-buffered K tile (swizzled content)
  __shared__ u16 VtsB[2 * 4096];  // double-buffered V^T tile (swizzled content)
  __shared__ u16 Ps[128 * 64];    // P^T rows for both groups (wave-private)
  __shared__ float sXl[32];
  __shared__ float sAl[33];
  __shared__ float sBl[33];

  const int xi = blockIdx.x, h = blockIdx.y, b = blockIdx.z;
  const int flip = (b ^ (h >> 3)) & 1;
  const int j = flip ? (15 - xi) : xi;
  const int qt0 = 2 * j, qt1 = 2 * j + 1, ntiles = 2 * j + 2;

  const int tid = threadIdx.x, lane = tid & 63, wave = tid >> 6;
  const int li = lane & 15, quad = lane >> 4;
  const int bh = b * 16 + h;
  const u16* Qg = Q + (size_t)bh * 2048 * 64;
  const u16* Kg = K + (size_t)bh * 2048 * 64;
  const u16* Vg = Vt + (size_t)bh * 64 * 2048;

  const float cAbs = fabsf(cP[0]);
  const int u = segU[0];
  float x0 = INFF, A0, B0, A1, B1;
  A0 = segA[h]; B0 = segB[h]; A1 = A0; B1 = B0;
  if (u == 1) { x0 = segX[0]; A1 = segA[16 + h]; B1 = segB[16 + h]; }
  if (u > 1) {
    if (tid < u) sXl[tid] = segX[tid];
    if (tid < u + 1) { sAl[tid] = segA[tid * 16 + h]; sBl[tid] = segB[tid * 16 + h]; }
  }
  const float A0e = A0 * LOG2E, A1e = A1 * LOG2E;
  const float SCL = 0.125f * LOG2E;
  // fast path: all rlv>=0 take the hi segment (x0<=0) and the additive A
  // cancels in softmax (A0e==A1e). True for b1=0 data (single crossing at 0).
  const bool uniB = (u <= 1) && (x0 <= 0.0f) && (A0e == A1e);

  const int t0 = j * 128 + wave * 16 + li;  // group 0 q-row
  const int t1 = t0 + 64;                   // group 1 q-row
  bf16x8 qf0[2], qf1[2];
#pragma unroll
  for (int c = 0; c < 2; c++) {
    qf0[c] = *(const bf16x8*)(Qg + (size_t)t0 * 64 + c * 32 + quad * 8);
    qf1[c] = *(const bf16x8*)(Qg + (size_t)t1 * 64 + c * 32 + quad * 8);
  }
  const float gI0 = ig2[t0], gI1 = ig2[t1];
  const float x0r0 = x0 / gI0, x0r1 = x0 / gI1;
  const float B0g0 = B0 * gI0 * LOG2E, B1g0 = B1 * gI0 * LOG2E;
  const float B0g1 = B0 * gI1 * LOG2E, B1g1 = B1 * gI1 * LOG2E;

  float m0 = -INFF, l0 = 0.0f, m1 = -INFF, l1 = 0.0f;
  f32x4 o0[4], o1[4];
#pragma unroll
  for (int nt = 0; nt < 4; nt++) {
    o0[nt] = (f32x4){0.f, 0.f, 0.f, 0.f};
    o1[nt] = (f32x4){0.f, 0.f, 0.f, 0.f};
  }

  // per-lane staging bases (16B per lane, 1KB per wave per call)
  const u16* kgB = Kg + (size_t)(wave * 16 + (lane >> 3)) * 64 + (lane & 7) * 8;
  const u16* vgB = Vg + (size_t)(wave * 16 + (lane >> 3)) * 2048 + (lane & 7) * 8;

  auto stage = [&](int buf, int kt2) {
    u16* kd = KsB + buf * 4096 + wave * 1024;
    const u16* kg = kgB + (size_t)kt2 * 4096;
    stage1k(kg, kd, lane);
    stage1k(kg + 8 * 64, kd + 512, lane);
    u16* vd = VtsB + buf * 4096 + wave * 1024;
    const u16* vg = vgB + kt2 * 64;
    stage1k(vg, vd, lane);
    stage1k(vg + 8 * 2048, vd + 512, lane);
  };

  stage(0, 0);
  int cur = 0;

  for (int kt = 0; kt < ntiles; kt++) {
    const int kb = kt * 64;
    __syncthreads();  // drains this wave's glds (vmcnt 0) + all waves arrived
    if (kt + 1 < ntiles) stage(cur ^ 1, kt + 1);  // overlaps compute below

    u16* KsT = KsB + cur * 4096;
    u16* VtT = VtsB + cur * 4096;

    // S^T = K Q^T for both groups; each kf fragment feeds 2 MFMAs
    f32x4 s0[4], s1[4];
#pragma unroll
    for (int nt = 0; nt < 4; nt++) {
      s0[nt] = (f32x4){0.f, 0.f, 0.f, 0.f};
      s1[nt] = (f32x4){0.f, 0.f, 0.f, 0.f};
    }
    __builtin_amdgcn_s_setprio(1);
#pragma unroll
    for (int c = 0; c < 2; c++)
#pragma unroll
      for (int nt = 0; nt < 4; nt++) {
        bf16x8 kf = *(const bf16x8*)swzp(KsT, nt * 16 + li, c * 64 + quad * 16);
        s0[nt] = __builtin_amdgcn_mfma_f32_16x16x32_bf16(kf, qf0[c], s0[nt], 0, 0, 0);
        s1[nt] = __builtin_amdgcn_mfma_f32_16x16x32_bf16(kf, qf1[c], s1[nt], 0, 0, 0);
      }
    __builtin_amdgcn_s_setprio(0);

    // bias in registers: rlv = log2(c*(t-k)+1) via v_log_f32
    const float dq0 = (float)(t0 - kb - quad * 4);
    const float dq1 = dq0 + 64.0f;
    if (uniB) {
#pragma unroll
      for (int nt = 0; nt < 4; nt++)
#pragma unroll
        for (int r = 0; r < 4; r++) {
          float rl0 = __builtin_amdgcn_logf(fmaf(cAbs, dq0 - nt * 16 - r, 1.0f));
          float rl1 = __builtin_amdgcn_logf(fmaf(cAbs, dq1 - nt * 16 - r, 1.0f));
          s0[nt][r] = fmaf(rl0, B1g0, s0[nt][r] * SCL);
          s1[nt][r] = fmaf(rl1, B1g1, s1[nt][r] * SCL);
        }
    } else if (u <= 1) {
#pragma unroll
      for (int nt = 0; nt < 4; nt++)
#pragma unroll
        for (int r = 0; r < 4; r++) {
          float rl0 = __builtin_amdgcn_logf(fmaf(cAbs, dq0 - nt * 16 - r, 1.0f));
          float rl1 = __builtin_amdgcn_logf(fmaf(cAbs, dq1 - nt * 16 - r, 1.0f));
          bool h0 = rl0 > x0r0, h1 = rl1 > x0r1;
          float z0 = fmaf(rl0, h0 ? B1g0 : B0g0, h0 ? A1e : A0e);
          float z1 = fmaf(rl1, h1 ? B1g1 : B0g1, h1 ? A1e : A0e);
          s0[nt][r] = fmaf(s0[nt][r], SCL, z0);
          s1[nt][r] = fmaf(s1[nt][r], SCL, z1);
        }
    } else {
#pragma unroll
      for (int nt = 0; nt < 4; nt++)
#pragma unroll
        for (int r = 0; r < 4; r++) {
          float rl0 = __builtin_amdgcn_logf(fmaf(cAbs, dq0 - nt * 16 - r, 1.0f));
          float rl1 = __builtin_amdgcn_logf(fmaf(cAbs, dq1 - nt * 16 - r, 1.0f));
          float nd0 = rl0 * gI0, nd1 = rl1 * gI1;
          int j0 = 0, j1 = 0;
          for (int i = 0; i < u; i++) {
            j0 += (nd0 > sXl[i]) ? 1 : 0;
            j1 += (nd1 > sXl[i]) ? 1 : 0;
          }
          s0[nt][r] = (fmaf(nd0, sBl[j0], sAl[j0]) + s0[nt][r] * 0.125f) * LOG2E;
          s1[nt][r] = (fmaf(nd1, sBl[j1], sAl[j1]) + s1[nt][r] * 0.125f) * LOG2E;
        }
    }

    // causal masks, hoisted (uniform branches; g0 fully masked on its dead
    // tail tile kt==qt0+1, making it a clean no-op)
    if (kt >= qt0) {
      const int lim0 = t0 - kb - quad * 4;
#pragma unroll
      for (int nt = 0; nt < 4; nt++)
#pragma unroll
        for (int r = 0; r < 4; r++)
          if (nt * 16 + r > lim0) s0[nt][r] = -INFF;
    }
    if (kt == qt1) {
      const int lim1 = t1 - kb - quad * 4;
#pragma unroll
      for (int nt = 0; nt < 4; nt++)
#pragma unroll
        for (int r = 0; r < 4; r++)
          if (nt * 16 + r > lim1) s1[nt][r] = -INFF;
    }

    // online softmax, two independent chains (ILP)
    {
      f32x4 mm0 = s0[0], mm1 = s1[0];
#pragma unroll
      for (int nt = 1; nt < 4; nt++)
#pragma unroll
        for (int r = 0; r < 4; r++) {
          mm0[r] = fmaxf(mm0[r], s0[nt][r]);
          mm1[r] = fmaxf(mm1[r], s1[nt][r]);
        }
      float v0 = fmaxf(fmaxf(mm0[0], mm0[1]), fmaxf(mm0[2], mm0[3]));
      float v1 = fmaxf(fmaxf(mm1[0], mm1[1]), fmaxf(mm1[2], mm1[3]));
      v0 = fmaxf(v0, __shfl_xor(v0, 16, 64));
      v1 = fmaxf(v1, __shfl_xor(v1, 16, 64));
      v0 = fmaxf(v0, __shfl_xor(v0, 32, 64));
      v1 = fmaxf(v1, __shfl_xor(v1, 32, 64));
      float mn0 = fmaxf(m0, v0), mn1 = fmaxf(m1, v1);
      bool g0 = mn0 > m0, g1 = mn1 > m1;
      float a0 = __builtin_amdgcn_exp2f(m0 - mn0);
      float a1 = __builtin_amdgcn_exp2f(m1 - mn1);
      m0 = mn0; m1 = mn1;
#pragma unroll
      for (int nt = 0; nt < 4; nt++)
#pragma unroll
        for (int r = 0; r < 4; r++) {
          s0[nt][r] = __builtin_amdgcn_exp2f(s0[nt][r] - mn0);
          s1[nt][r] = __builtin_amdgcn_exp2f(s1[nt][r] - mn1);
        }
      f32x4 sv0 = (s0[0] + s0[1]) + (s0[2] + s0[3]);
      f32x4 sv1 = (s1[0] + s1[1]) + (s1[2] + s1[3]);
      float ss0 = (sv0[0] + sv0[1]) + (sv0[2] + sv0[3]);
      float ss1 = (sv1[0] + sv1[1]) + (sv1[2] + sv1[3]);
      ss0 += __shfl_xor(ss0, 16, 64);
      ss1 += __shfl_xor(ss1, 16, 64);
      ss0 += __shfl_xor(ss0, 32, 64);
      ss1 += __shfl_xor(ss1, 32, 64);
      l0 = l0 * a0 + ss0;
      l1 = l1 * a1 + ss1;
      if (__any(g0)) {
#pragma unroll
        for (int nt = 0; nt < 4; nt++)
#pragma unroll
          for (int r = 0; r < 4; r++) o0[nt][r] *= a0;
      }
      if (__any(g1)) {
#pragma unroll
        for (int nt = 0; nt < 4; nt++)
#pragma unroll
          for (int r = 0; r < 4; r++) o1[nt][r] *= a1;
      }
    }

    // P^T -> Ps rows (g*64 + wave*16 + li); wave-private, b64 writes
    const int pr0 = wave * 16 + li, pr1 = pr0 + 64;
#pragma unroll
    for (int nt = 0; nt < 4; nt++) {
      uint2 pk0, pk1;
      pk0.x = pack2bf(s0[nt][0], s0[nt][1]);
      pk0.y = pack2bf(s0[nt][2], s0[nt][3]);
      pk1.x = pack2bf(s1[nt][0], s1[nt][1]);
      pk1.y = pack2bf(s1[nt][2], s1[nt][3]);
      *(uint2*)swzp(Ps, pr0, 32 * nt + 8 * quad) = pk0;
      *(uint2*)swzp(Ps, pr1, 32 * nt + 8 * quad) = pk1;
    }

    // O^T += V^T P^T for both groups; each vf fragment feeds 2 MFMAs
    __builtin_amdgcn_s_setprio(1);
#pragma unroll
    for (int c = 0; c < 2; c++) {
      bf16x8 pf0 = *(const bf16x8*)swzp(Ps, pr0, c * 64 + quad * 16);
      bf16x8 pf1 = *(const bf16x8*)swzp(Ps, pr1, c * 64 + quad * 16);
#pragma unroll
      for (int nt = 0; nt < 4; nt++) {
        bf16x8 vf = *(const bf16x8*)swzp(VtT, nt * 16 + li, c * 64 + quad * 16);
        o0[nt] = __builtin_amdgcn_mfma_f32_16x16x32_bf16(vf, pf0, o0[nt], 0, 0, 0);
        o1[nt] = __builtin_amdgcn_mfma_f32_16x16x32_bf16(vf, pf1, o1[nt], 0, 0, 0);
      }
    }
    __builtin_amdgcn_s_setprio(0);
    cur ^= 1;
  }

  // epilogue: O^T element (d = nt*16+quad*4+r, q = li) -> Y[b][t][h*64+d]
  const float i0 = 1.0f / l0, i1 = 1.0f / l1;
  u16* d0 = Y + (size_t)(b * 2048 + t0) * 1024 + h * 64 + quad * 4;
  u16* d1 = Y + (size_t)(b * 2048 + t1) * 1024 + h * 64 + quad * 4;
#pragma unroll
  for (int nt = 0; nt < 4; nt++) {
    uint2 pk0, pk1;
    pk0.x = pack2bf(o0[nt][0] * i0, o0[nt][1] * i0);
    pk0.y = pack2bf(o0[nt][2] * i0, o0[nt][3] * i0);
    pk1.x = pack2bf(o1[nt][0] * i1, o1[nt][1] * i1);
    pk1.y = pack2bf(o1[nt][2] * i1, o1[nt][3] * i1);
    *(uint2*)(d0 + nt * 16) = pk0;
    *(uint2*)(d1 + nt * 16) = pk1;
  }
}

// ---------------- launcher ----------------
extern "C" void kernel_launch(void* const* d_in, const int* in_sizes, int n_in,
                              void* d_out, int out_size, void* d_ws, size_t ws_size,
                              hipStream_t stream) {
  (void)in_sizes; (void)n_in; (void)out_size; (void)ws_size;
  const float* x = (const float*)d_in[0];
  const float* Wqkv = (const float*)d_in[1];
  const float* bqkv = (const float*)d_in[2];
  const float* Wproj = (const float*)d_in[3];
  const float* bproj = (const float*)d_in[4];
  const float* w1 = (const float*)d_in[5];
  const float* b1 = (const float*)d_in[6];
  const float* w2 = (const float*)d_in[7];
  const float* b2 = (const float*)d_in[8];
  const float* cP = (const float*)d_in[9];
  const float* lP = (const float*)d_in[10];

  char* ws = (char*)d_ws;
  u16* Xbf = (u16*)(ws);                          // 8 MB
  u16* WqkvT = (u16*)(ws + (size_t)(8 << 20));    // 6 MB
  u16* WprojT = (u16*)(ws + (size_t)(14 << 20));  // 2 MB
  u16* Qb = (u16*)(ws + (size_t)(16 << 20));      // 8 MB  [bh][t][d]
  u16* Kb = (u16*)(ws + (size_t)(24 << 20));      // 8 MB  [bh][t][d] swizzled
  u16* Vb = (u16*)(ws + (size_t)(32 << 20));      // 8 MB  [bh][d][t] swizzled
  u16* Yb = (u16*)(ws + (size_t)(40 << 20));      // 8 MB
  float* IG = (float*)(ws + (size_t)(48 << 20));  // tables
  float* SEGX = IG + 2048;
  float* SEGA = SEGX + 32;
  float* SEGB = SEGA + 33 * 16;
  int* SEGU = (int*)(SEGB + 33 * 16);

  k_convert_x<<<4096, 256, 0, stream>>>(x, Xbf, 1048576);
  k_transpose_bf<<<dim3(96, 32), dim3(32, 8), 0, stream>>>(Wqkv, WqkvT, 1024, 3072);
  k_transpose_bf<<<dim3(32, 32), dim3(32, 8), 0, stream>>>(Wproj, WprojT, 1024, 1024);
  k_tables<<<8, 256, 0, stream>>>(cP, lP, IG);
  k_segments<<<1, 64, 0, stream>>>(w1, b1, w2, b2, SEGX, SEGA, SEGB, SEGU);

  k_gemm<0, 128><<<dim3(24, 32), 256, 0, stream>>>(Xbf, WqkvT, bqkv, nullptr, Qb, Kb, Vb,
                                                   4096, 3072, 1024);
  k_attn<<<dim3(16, 16, 2), 256, 0, stream>>>(Qb, Kb, Vb, Yb, IG, cP, SEGX, SEGA, SEGB, SEGU);
  k_gemm<1, 64><<<dim3(16, 32), 256, 0, stream>>>(Yb, WprojT, bproj, (float*)d_out, nullptr,
                                                  nullptr, nullptr, 4096, 1024, 1024);
}

// Round 7
// 234.627 us; speedup vs baseline: 1.1921x; 1.1921x over previous
//
#include <hip/hip_runtime.h>
#include <cstdint>

typedef unsigned short u16;
typedef unsigned int u32;

typedef short bf16x8 __attribute__((ext_vector_type(8)));
typedef float f32x4 __attribute__((ext_vector_type(4)));

#define LN2 0.69314718055994530942f
#define LOG2E 1.44269504088896340736f
#define INFF __builtin_inff()

__device__ __forceinline__ u16 f2bf(float f) {
  u32 u = __float_as_uint(f);
  u = (u + 0x7fffu + ((u >> 16) & 1u)) >> 16;
  return (u16)u;
}
__device__ __forceinline__ u32 pack2bf(float a, float b) {
  u32 ta = __float_as_uint(a) + 0x8000u;
  u32 tb = __float_as_uint(b) + 0x8000u;
  return __builtin_amdgcn_perm(tb, ta, 0x07060302u);
}

#if __has_builtin(__builtin_amdgcn_global_load_lds)
#define HAVE_GLDS 1
__device__ __forceinline__ void glds16(const u16* g, u16* l) {
  __builtin_amdgcn_global_load_lds((const __attribute__((address_space(1))) void*)g,
                                   (__attribute__((address_space(3))) void*)l, 16, 0, 0);
}
#else
#define HAVE_GLDS 0
#endif

// stage 1KB per wave: per-lane global source gperlane (16B each), wave-uniform
// LDS dest lwave (HW adds lane*16B for glds; fallback does it manually).
__device__ __forceinline__ void stage1k(const u16* gperlane, u16* lwave, int lane) {
#if HAVE_GLDS
  (void)lane;
  glds16(gperlane, lwave);
#else
  *(uint4*)(lwave + lane * 8) = *(const uint4*)gperlane;
#endif
}

// XOR-swizzled LDS addressing for [R][64] u16 tiles (128B rows).
// byte ^= ((row&7)<<4). Measured: kills the stride-128B same-bank pattern
// (SQ_LDS_BANK_CONFLICT 5.9M -> 1.08M). K/V arrive in global memory ALREADY
// swizzled, so staging is a pure linear async copy; only reads use swzp.
__device__ __forceinline__ u16* swzp(u16* base, int row, int bc) {
  return (u16*)((char*)base + row * 128 + (bc ^ ((row & 7) << 4)));
}

// ---------------- prep kernels ----------------

__global__ void k_convert_x(const float* __restrict__ in, u16* __restrict__ out, int n4) {
  int i = blockIdx.x * blockDim.x + threadIdx.x;
  if (i < n4) {
    float4 v = ((const float4*)in)[i];
    ushort4 o;
    o.x = f2bf(v.x); o.y = f2bf(v.y); o.z = f2bf(v.z); o.w = f2bf(v.w);
    ((ushort4*)out)[i] = o;
  }
}

__global__ void k_transpose_bf(const float* __restrict__ in, u16* __restrict__ out, int R, int C) {
  __shared__ float t[32][33];
  int c0 = blockIdx.x * 32, r0 = blockIdx.y * 32;
  int tx = threadIdx.x, ty = threadIdx.y;
#pragma unroll
  for (int k = 0; k < 4; k++) t[ty + 8 * k][tx] = in[(size_t)(r0 + ty + 8 * k) * C + c0 + tx];
  __syncthreads();
#pragma unroll
  for (int k = 0; k < 4; k++) out[(size_t)(c0 + ty + 8 * k) * R + r0 + tx] = f2bf(t[tx][ty + 8 * k]);
}

__global__ void k_tables(const float* __restrict__ cP, const float* __restrict__ lP,
                         float* __restrict__ ig2) {
  int t = blockIdx.x * blockDim.x + threadIdx.x;
  float c = fabsf(cP[0]);
  if (t < 2048) {
    float lm = lP[0];
    float thr = fabsf(lm * 512.0f);
    float pn = fmaxf((float)t, thr);
    float den = logf(c * pn + 1.0f) + 1e-6f;
    ig2[t] = LN2 / den;
  }
}

// V transpose: [bh][t][d] linear -> [bh][d][t] with t-index swizzle ^((d&7)<<3)
// (u16 units). 16MB traffic, memory-bound; lets the GEMM keep coalesced V
// stores (round-4's in-GEMM transposed store scattered 8B across 4KB-apart
// rows: ~16x line waste, ~+10us on GEMM1).
__global__ void k_vt(const u16* __restrict__ Vin, u16* __restrict__ Vout) {
  __shared__ u16 ts[64][72];
  const int tb = blockIdx.x, bh = blockIdx.y;
  const int tid = threadIdx.x;
  const int row = tid >> 2, c16 = (tid & 3) * 16;
  const u16* src = Vin + (size_t)bh * 2048 * 64 + (size_t)(tb * 64 + row) * 64 + c16;
  *(uint4*)&ts[row][c16] = *(const uint4*)src;
  *(uint4*)&ts[row][c16 + 8] = *(const uint4*)(src + 8);
  __syncthreads();
  u16* drow = Vout + (size_t)bh * 64 * 2048 + (size_t)row * 2048 + tb * 64;
  const int s = (row & 7) << 3;
  u16 tmp[16];
#pragma unroll
  for (int k = 0; k < 16; k++) tmp[k] = ts[c16 + k][row];
  *(uint4*)(drow + (c16 ^ s)) = *(uint4*)&tmp[0];
  *(uint4*)(drow + ((c16 + 8) ^ s)) = *(uint4*)&tmp[8];
}

__global__ void k_segments(const float* __restrict__ w1, const float* __restrict__ b1,
                           const float* __restrict__ w2, const float* __restrict__ b2,
                           float* __restrict__ segX, float* __restrict__ segA,
                           float* __restrict__ segB, int* __restrict__ segU) {
  __shared__ float xs[32];
  __shared__ float srt[32];
  __shared__ float uniq[32];
  __shared__ int uCnt;
  int t = threadIdx.x;
  if (t < 32) {
    float w = w1[t], b = b1[t];
    xs[t] = (w != 0.0f) ? (-b / w) : INFF;
  }
  __syncthreads();
  if (t < 32) {
    float x = xs[t];
    int r = 0;
    for (int v = 0; v < 32; v++) {
      float xv = xs[v];
      if (xv < x || (xv == x && v < t)) r++;
    }
    srt[r] = x;
  }
  __syncthreads();
  if (t == 0) {
    int u = 0;
    for (int i = 0; i < 32; i++) {
      float v = srt[i];
      if (v < 3.0e38f && (u == 0 || v != uniq[u - 1])) uniq[u++] = v;
    }
    uCnt = u;
    segU[0] = u;
  }
  __syncthreads();
  int u = uCnt;
  if (t < u) segX[t] = uniq[t];
  for (int idx = t; idx < (u + 1) * 16; idx += blockDim.x) {
    int j = idx >> 4, h = idx & 15;
    float p;
    if (u == 0) p = 0.0f;
    else if (j == 0) p = uniq[0] - 1.0f;
    else if (j == u) p = uniq[u - 1] + 1.0f;
    else p = 0.5f * (uniq[j - 1] + uniq[j]);
    float A = b2[h], B = 0.0f;
    for (int w = 0; w < 32; w++) {
      float w1w = w1[w], b1w = b1[w], w2wh = w2[w * 16 + h];
      if (w1w != 0.0f) {
        if (fmaf(w1w, p, b1w) > 0.0f) { B += w1w * w2wh; A += b1w * w2wh; }
      } else if (b1w > 0.0f) {
        A += b1w * w2wh;
      }
    }
    segA[j * 16 + h] = A;
    segB[j * 16 + h] = B;
  }
}

// ---------------- GEMM:  C(MxN) = A(MxK) @ BT(NxK)^T ----------------
// MODE 0 (QKV): Q,V -> [bh][t][d] linear (coalesced scalar stores); K ->
// [bh][t][d] with per-row u16 swizzle ^((t&7)<<3). V's transposed layout is
// produced by k_vt afterwards.
template <int MODE, int BN>
__launch_bounds__(256, 3)
__global__ void k_gemm(const u16* __restrict__ A, const u16* __restrict__ BT,
                       const float* __restrict__ bias, float* __restrict__ outF,
                       u16* __restrict__ outQ, u16* __restrict__ outK, u16* __restrict__ outV,
                       int M, int N, int K) {
  constexpr int NT = BN / 32;
  constexpr int NCH = BN / 32;
  __shared__ u16 As[128 * 64];
  __shared__ u16 Bs[BN * 64];
  const int tid = threadIdx.x;
  const int lane = tid & 63, wave = tid >> 6;
  const int li = lane & 15, quad = lane >> 4;
  const int wrow = (wave >> 1) * 64, wcol = (wave & 1) * (BN / 2);
  const int rb = blockIdx.y * 128, cb = blockIdx.x * BN;

  f32x4 acc[4][NT];
#pragma unroll
  for (int i = 0; i < 4; i++)
#pragma unroll
    for (int j = 0; j < NT; j++) acc[i][j] = (f32x4){0.f, 0.f, 0.f, 0.f};

#if HAVE_GLDS
  const u16* gA = A + (size_t)(rb + (tid >> 3)) * K + (tid & 7) * 8;
  const u16* gB = BT + (size_t)(cb + (tid >> 3)) * K + (tid & 7) * 8;
  u16* lA = As + wave * 512;
  u16* lB = Bs + wave * 512;

  for (int k0 = 0; k0 < K; k0 += 64) {
    __syncthreads();
#pragma unroll
    for (int ch = 0; ch < 4; ch++) glds16(gA + (size_t)ch * 32 * K + k0, lA + ch * 2048);
#pragma unroll
    for (int ch = 0; ch < NCH; ch++) glds16(gB + (size_t)ch * 32 * K + k0, lB + ch * 2048);
    __syncthreads();
#pragma unroll
    for (int c = 0; c < 2; c++) {
      bf16x8 af[4], bfr[NT];
#pragma unroll
      for (int mt = 0; mt < 4; mt++)
        af[mt] = *(const bf16x8*)(&As[(wrow + mt * 16 + li) * 64 + c * 32 + quad * 8]);
#pragma unroll
      for (int nt = 0; nt < NT; nt++)
        bfr[nt] = *(const bf16x8*)(&Bs[(wcol + nt * 16 + li) * 64 + c * 32 + quad * 8]);
#pragma unroll
      for (int mt = 0; mt < 4; mt++)
#pragma unroll
        for (int nt = 0; nt < NT; nt++)
          acc[mt][nt] = __builtin_amdgcn_mfma_f32_16x16x32_bf16(af[mt], bfr[nt], acc[mt][nt], 0, 0, 0);
    }
  }
#else
  for (int k0 = 0; k0 < K; k0 += 64) {
    __syncthreads();
    for (int idx = tid * 8; idx < 128 * 64; idx += 256 * 8) {
      int rr = idx >> 6, cc = idx & 63;
      *(uint4*)(&As[idx]) = *(const uint4*)(A + (size_t)(rb + rr) * K + k0 + cc);
    }
    for (int idx = tid * 8; idx < BN * 64; idx += 256 * 8) {
      int rr = idx >> 6, cc = idx & 63;
      *(uint4*)(&Bs[idx]) = *(const uint4*)(BT + (size_t)(cb + rr) * K + k0 + cc);
    }
    __syncthreads();
#pragma unroll
    for (int c = 0; c < 2; c++) {
      bf16x8 af[4], bfr[NT];
#pragma unroll
      for (int mt = 0; mt < 4; mt++)
        af[mt] = *(const bf16x8*)(&As[(wrow + mt * 16 + li) * 64 + c * 32 + quad * 8]);
#pragma unroll
      for (int nt = 0; nt < NT; nt++)
        bfr[nt] = *(const bf16x8*)(&Bs[(wcol + nt * 16 + li) * 64 + c * 32 + quad * 8]);
#pragma unroll
      for (int mt = 0; mt < 4; mt++)
#pragma unroll
        for (int nt = 0; nt < NT; nt++)
          acc[mt][nt] = __builtin_amdgcn_mfma_f32_16x16x32_bf16(af[mt], bfr[nt], acc[mt][nt], 0, 0, 0);
    }
  }
#endif

#pragma unroll
  for (int mt = 0; mt < 4; mt++)
#pragma unroll
    for (int nt = 0; nt < NT; nt++) {
      const int col = cb + wcol + nt * 16 + li;
      const int row0 = rb + wrow + mt * 16 + quad * 4;
      float v[4];
#pragma unroll
      for (int r = 0; r < 4; r++) v[r] = acc[mt][nt][r] + bias[col];
      if (MODE == 0) {
        const int bb = row0 >> 11, tt0 = row0 & 2047;
        const int sel = col >> 10, w = col & 1023, hh = w >> 6, dd = w & 63;
        if (sel == 0) {
          u16* dst = outQ + ((size_t)((bb * 16 + hh) * 2048 + tt0)) * 64 + dd;
#pragma unroll
          for (int r = 0; r < 4; r++) dst[(size_t)r * 64] = f2bf(v[r]);
        } else if (sel == 1) {
          // K: row-swizzled [bh][t][d]
          u16* base = outK + ((size_t)((bb * 16 + hh) * 2048 + tt0)) * 64;
#pragma unroll
          for (int r = 0; r < 4; r++) {
            int tt = tt0 + r;
            base[(size_t)r * 64 + (dd ^ ((tt & 7) << 3))] = f2bf(v[r]);
          }
        } else {
          // V: linear [bh][t][d] (coalesced); k_vt transposes afterwards
          u16* dst = outV + ((size_t)((bb * 16 + hh) * 2048 + tt0)) * 64 + dd;
#pragma unroll
          for (int r = 0; r < 4; r++) dst[(size_t)r * 64] = f2bf(v[r]);
        }
      } else {
#pragma unroll
        for (int r = 0; r < 4; r++) outF[(size_t)(row0 + r) * N + col] = v[r];
      }
    }
}

// ---------------- flash attention, S^T formulation, 8-wave blocks ----------
// History: per-wave structure proven at 77us (round 4; VGPR 72, VALUBusy 31%,
// all pipes idle -> latency-bound). Round 5/6: doubling work per WAVE needs
// ~300 regs -> spills at cap 256, kills residency uncapped. This round:
// double work per BLOCK instead -- 512 threads / 8 waves / 128 q-rows. Same
// per-wave register footprint; K/V staged once per 128 rows (stage+barrier
// cost per unit work halves), and residency doubles: 2 blocks x 8 waves = 16
// waves/CU = 4 waves/SIMD (vs ~2 at round 4).
// __launch_bounds__(512,4): 4 waves/EU -> reg cap 128 (need ~90, no spill).
// Waves 0-3 idle through one fully-masked tail tile (verified no-op: all
// -INF -> exp2 0, alpha 1). Pairing flip=(b^(h>>3))&1 keeps per-CU sums ~34.
__launch_bounds__(512, 4)
__global__ void k_attn(const u16* __restrict__ Q, const u16* __restrict__ K,
                       const u16* __restrict__ Vt, u16* __restrict__ Y,
                       const float* __restrict__ ig2, const float* __restrict__ cP,
                       const float* __restrict__ segX, const float* __restrict__ segA,
                       const float* __restrict__ segB, const int* __restrict__ segU) {
  __shared__ u16 KsB[2 * 4096];   // double-buffered K tile (64x64, swizzled)
  __shared__ u16 VtsB[2 * 4096];  // double-buffered V^T tile (swizzled)
  __shared__ u16 Ps[128 * 64];    // P^T rows for all 8 waves (wave-private)
  __shared__ float sXl[32];
  __shared__ float sAl[33];
  __shared__ float sBl[33];

  const int xi = blockIdx.x, h = blockIdx.y, b = blockIdx.z;
  const int flip = (b ^ (h >> 3)) & 1;
  const int j = flip ? (15 - xi) : xi;       // q super-tile: rows [128j,128j+128)
  const int ntiles = 2 * j + 2;

  const int tid = threadIdx.x, lane = tid & 63, wave = tid >> 6;
  const int li = lane & 15, quad = lane >> 4;
  const int qtw = 2 * j + (wave >> 2);       // this wave's diagonal tile
  const int bh = b * 16 + h;
  const u16* Qg = Q + (size_t)bh * 2048 * 64;
  const u16* Kg = K + (size_t)bh * 2048 * 64;
  const u16* Vg = Vt + (size_t)bh * 64 * 2048;

  const float cAbs = fabsf(cP[0]);
  const int u = segU[0];
  float x0 = INFF, A0, B0, A1, B1;
  A0 = segA[h]; B0 = segB[h]; A1 = A0; B1 = B0;
  if (u == 1) { x0 = segX[0]; A1 = segA[16 + h]; B1 = segB[16 + h]; }
  if (u > 1) {
    if (tid < u) sXl[tid] = segX[tid];
    if (tid < u + 1) { sAl[tid] = segA[tid * 16 + h]; sBl[tid] = segB[tid * 16 + h]; }
  }
  const float A0e = A0 * LOG2E, A1e = A1 * LOG2E;
  const float SCL = 0.125f * LOG2E;
  // fast path: all rlv>=0 take the hi segment (x0<=0) and the additive A
  // cancels in softmax (A0e==A1e). True for b1=0 data (single crossing at 0).
  const bool uniB = (u <= 1) && (x0 <= 0.0f) && (A0e == A1e);

  const int t = j * 128 + wave * 16 + li;  // this lane's q-row
  bf16x8 qf[2];
#pragma unroll
  for (int c = 0; c < 2; c++)
    qf[c] = *(const bf16x8*)(Qg + (size_t)t * 64 + c * 32 + quad * 8);

  const float gI = ig2[t];
  const float x0r = x0 / gI;
  const float B0g = B0 * gI * LOG2E, B1g = B1 * gI * LOG2E;
  float mrow = -INFF, lrow = 0.0f;
  f32x4 oacc[4];
#pragma unroll
  for (int nt = 0; nt < 4; nt++) oacc[nt] = (f32x4){0.f, 0.f, 0.f, 0.f};

  // staging: 8 waves x 1KB each cover one 8KB K tile + one 8KB V tile.
  // wave w stages rows [8w, 8w+8): lane covers (row 8w+(lane>>3), 16B chunk
  // lane&7). Sources are pre-swizzled so the copy is linear.
  const u16* kgB = Kg + (size_t)(wave * 8 + (lane >> 3)) * 64 + (lane & 7) * 8;
  const u16* vgB = Vg + (size_t)(wave * 8 + (lane >> 3)) * 2048 + (lane & 7) * 8;

  auto stage = [&](int buf, int kt2) {
    stage1k(kgB + (size_t)kt2 * 4096, KsB + buf * 4096 + wave * 512, lane);
    stage1k(vgB + kt2 * 64, VtsB + buf * 4096 + wave * 512, lane);
  };

  stage(0, 0);
  int cur = 0;

  for (int kt = 0; kt < ntiles; kt++) {
    const int kb = kt * 64;
    __syncthreads();  // drains this wave's glds (vmcnt 0) + all waves arrived
    if (kt + 1 < ntiles) stage(cur ^ 1, kt + 1);  // overlaps compute below

    u16* KsT = KsB + cur * 4096;
    u16* VtT = VtsB + cur * 4096;

    // S^T = K Q^T : sacc[nt] row s = nt*16+quad*4+r, col q = li
    f32x4 sacc[4];
#pragma unroll
    for (int nt = 0; nt < 4; nt++) sacc[nt] = (f32x4){0.f, 0.f, 0.f, 0.f};
    __builtin_amdgcn_s_setprio(1);
#pragma unroll
    for (int c = 0; c < 2; c++)
#pragma unroll
      for (int nt = 0; nt < 4; nt++) {
        bf16x8 kf = *(const bf16x8*)swzp(KsT, nt * 16 + li, c * 64 + quad * 16);
        sacc[nt] = __builtin_amdgcn_mfma_f32_16x16x32_bf16(kf, qf[c], sacc[nt], 0, 0, 0);
      }
    __builtin_amdgcn_s_setprio(0);

    // bias in registers: rlv = log2(c*(t-k)+1) via v_log_f32
    const float dq = (float)(t - kb - quad * 4);
    if (uniB) {
#pragma unroll
      for (int nt = 0; nt < 4; nt++)
#pragma unroll
        for (int r = 0; r < 4; r++) {
          float rl = __builtin_amdgcn_logf(fmaf(cAbs, dq - nt * 16 - r, 1.0f));
          sacc[nt][r] = fmaf(rl, B1g, sacc[nt][r] * SCL);
        }
    } else if (u <= 1) {
#pragma unroll
      for (int nt = 0; nt < 4; nt++)
#pragma unroll
        for (int r = 0; r < 4; r++) {
          float rl = __builtin_amdgcn_logf(fmaf(cAbs, dq - nt * 16 - r, 1.0f));
          bool hi = rl > x0r;
          float z = fmaf(rl, hi ? B1g : B0g, hi ? A1e : A0e);
          sacc[nt][r] = fmaf(sacc[nt][r], SCL, z);
        }
    } else {
#pragma unroll
      for (int nt = 0; nt < 4; nt++)
#pragma unroll
        for (int r = 0; r < 4; r++) {
          float rl = __builtin_amdgcn_logf(fmaf(cAbs, dq - nt * 16 - r, 1.0f));
          float nd = rl * gI;
          int jj = 0;
          for (int i = 0; i < u; i++) jj += (nd > sXl[i]) ? 1 : 0;
          sacc[nt][r] = (fmaf(nd, sBl[jj], sAl[jj]) + sacc[nt][r] * 0.125f) * LOG2E;
        }
    }

    // causal mask, hoisted (uniform branch; for kt>qtw everything masks ->
    // clean no-op iteration for the lower-half waves on the last tile)
    if (kt >= qtw) {
      const int lim = t - kb - quad * 4;
#pragma unroll
      for (int nt = 0; nt < 4; nt++)
#pragma unroll
        for (int r = 0; r < 4; r++)
          if (nt * 16 + r > lim) sacc[nt][r] = -INFF;
    }

    // per-lane online softmax (row q = li) — tree-shaped max and sum
    f32x4 mm = sacc[0];
#pragma unroll
    for (int nt = 1; nt < 4; nt++)
#pragma unroll
      for (int r = 0; r < 4; r++) mm[r] = fmaxf(mm[r], sacc[nt][r]);
    float vm = fmaxf(fmaxf(mm[0], mm[1]), fmaxf(mm[2], mm[3]));
    vm = fmaxf(vm, __shfl_xor(vm, 16, 64));
    vm = fmaxf(vm, __shfl_xor(vm, 32, 64));
    float mnew = fmaxf(mrow, vm);
    bool grew = mnew > mrow;
    float alpha = __builtin_amdgcn_exp2f(mrow - mnew);
    mrow = mnew;
#pragma unroll
    for (int nt = 0; nt < 4; nt++)
#pragma unroll
      for (int r = 0; r < 4; r++)
        sacc[nt][r] = __builtin_amdgcn_exp2f(sacc[nt][r] - mnew);
    f32x4 sv = (sacc[0] + sacc[1]) + (sacc[2] + sacc[3]);
    float s = (sv[0] + sv[1]) + (sv[2] + sv[3]);
    s += __shfl_xor(s, 16, 64);
    s += __shfl_xor(s, 32, 64);
    lrow = lrow * alpha + s;
    if (__any(grew)) {  // skip the 16-mul rescale when no lane's max moved
#pragma unroll
      for (int nt = 0; nt < 4; nt++)
#pragma unroll
        for (int r = 0; r < 4; r++) oacc[nt][r] *= alpha;
    }

    // P^T -> Ps[q][s]; wave-private rows, b64 writes
    const int prow = wave * 16 + li;
#pragma unroll
    for (int nt = 0; nt < 4; nt++) {
      uint2 pk;
      pk.x = pack2bf(sacc[nt][0], sacc[nt][1]);
      pk.y = pack2bf(sacc[nt][2], sacc[nt][3]);
      *(uint2*)swzp(Ps, prow, 32 * nt + 8 * quad) = pk;
    }

    // O^T += V^T P^T
    __builtin_amdgcn_s_setprio(1);
#pragma unroll
    for (int c = 0; c < 2; c++) {
      bf16x8 pf = *(const bf16x8*)swzp(Ps, prow, c * 64 + quad * 16);
#pragma unroll
      for (int nt = 0; nt < 4; nt++) {
        bf16x8 vf = *(const bf16x8*)swzp(VtT, nt * 16 + li, c * 64 + quad * 16);
        oacc[nt] = __builtin_amdgcn_mfma_f32_16x16x32_bf16(vf, pf, oacc[nt], 0, 0, 0);
      }
    }
    __builtin_amdgcn_s_setprio(0);
    cur ^= 1;
  }

  // epilogue: O^T element (d = nt*16+quad*4+r, q = li) -> Y[b][t][h*64+d]
  float inv = 1.0f / lrow;
  u16* dst = Y + (size_t)(b * 2048 + t) * 1024 + h * 64 + quad * 4;
#pragma unroll
  for (int nt = 0; nt < 4; nt++) {
    uint2 pk;
    pk.x = pack2bf(oacc[nt][0] * inv, oacc[nt][1] * inv);
    pk.y = pack2bf(oacc[nt][2] * inv, oacc[nt][3] * inv);
    *(uint2*)(dst + nt * 16) = pk;
  }
}

// ---------------- launcher ----------------
extern "C" void kernel_launch(void* const* d_in, const int* in_sizes, int n_in,
                              void* d_out, int out_size, void* d_ws, size_t ws_size,
                              hipStream_t stream) {
  (void)in_sizes; (void)n_in; (void)out_size; (void)ws_size;
  const float* x = (const float*)d_in[0];
  const float* Wqkv = (const float*)d_in[1];
  const float* bqkv = (const float*)d_in[2];
  const float* Wproj = (const float*)d_in[3];
  const float* bproj = (const float*)d_in[4];
  const float* w1 = (const float*)d_in[5];
  const float* b1 = (const float*)d_in[6];
  const float* w2 = (const float*)d_in[7];
  const float* b2 = (const float*)d_in[8];
  const float* cP = (const float*)d_in[9];
  const float* lP = (const float*)d_in[10];

  // Workspace (MB):
  //  [0,8)   Xbf (prep; dead after GEMM1) -> reused as Vtb (k_vt output)
  //  [8,14)  WqkvT   [14,16) WprojT
  //  [16,24) Qb  [24,32) Kb (swizzled)  [32,40) Vlin  [40,48) Yb
  //  [48,..) tables
  char* ws = (char*)d_ws;
  u16* Xbf = (u16*)(ws);
  u16* WqkvT = (u16*)(ws + (size_t)(8 << 20));
  u16* WprojT = (u16*)(ws + (size_t)(14 << 20));
  u16* Qb = (u16*)(ws + (size_t)(16 << 20));
  u16* Kb = (u16*)(ws + (size_t)(24 << 20));
  u16* Vlin = (u16*)(ws + (size_t)(32 << 20));
  u16* Yb = (u16*)(ws + (size_t)(40 << 20));
  u16* Vtb = (u16*)(ws);  // overlays Xbf, valid after GEMM1
  float* IG = (float*)(ws + (size_t)(48 << 20));
  float* SEGX = IG + 2048;
  float* SEGA = SEGX + 32;
  float* SEGB = SEGA + 33 * 16;
  int* SEGU = (int*)(SEGB + 33 * 16);

  k_convert_x<<<4096, 256, 0, stream>>>(x, Xbf, 1048576);
  k_transpose_bf<<<dim3(96, 32), dim3(32, 8), 0, stream>>>(Wqkv, WqkvT, 1024, 3072);
  k_transpose_bf<<<dim3(32, 32), dim3(32, 8), 0, stream>>>(Wproj, WprojT, 1024, 1024);
  k_tables<<<8, 256, 0, stream>>>(cP, lP, IG);
  k_segments<<<1, 64, 0, stream>>>(w1, b1, w2, b2, SEGX, SEGA, SEGB, SEGU);

  k_gemm<0, 128><<<dim3(24, 32), 256, 0, stream>>>(Xbf, WqkvT, bqkv, nullptr, Qb, Kb, Vlin,
                                                   4096, 3072, 1024);
  k_vt<<<dim3(32, 32), 256, 0, stream>>>(Vlin, Vtb);
  k_attn<<<dim3(16, 16, 2), 512, 0, stream>>>(Qb, Kb, Vtb, Yb, IG, cP, SEGX, SEGA, SEGB, SEGU);
  k_gemm<1, 64><<<dim3(16, 32), 256, 0, stream>>>(Yb, WprojT, bproj, (float*)d_out, nullptr,
                                                  nullptr, nullptr, 4096, 1024, 1024);
}